// Round 12
// baseline (819.309 us; speedup 1.0000x reference)
//
#include <hip/hip_runtime.h>
#include <hip/hip_bf16.h>

// ---------------------------------------------------------------------------
// Transformer encoder, B=8 T=1024 D_IN=320 L=6 H=8 DK=DV=64 DM=512 DI=2048.
// R11: tile balance + tcvt fusion -> 803us.
// R12: (a) w2 split-K x2 (K=2048 -> 2x1024; halves the 32-step serial
//   barrier chain, doubles parallelism; f32 partials, bias in half 0 only;
//   ln2_res_k sums partials). (b) qkv BM64xBN128 (49KB LDS -> 3/CU, was
//   2/CU cap + tail). (c) input projection writes bf16.
// ---------------------------------------------------------------------------

typedef unsigned short bh16;                                  // bf16 bits
typedef __bf16 bf16x8 __attribute__((ext_vector_type(8)));
typedef float f32x4 __attribute__((ext_vector_type(4)));
typedef unsigned int u32x4 __attribute__((ext_vector_type(4)));
typedef unsigned int u32x2 __attribute__((ext_vector_type(2)));

#define DEVI static __device__ __forceinline__

DEVI bh16 f2bf(float f) {
  union { float f; unsigned u; } x; x.f = f;
  unsigned r = x.u + 0x7fffu + ((x.u >> 16) & 1u);
  return (bh16)(r >> 16);
}
DEVI float bf2f(bh16 u) {
  union { unsigned u; float f; } x; x.u = ((unsigned)u) << 16; return x.f;
}
DEVI bf16x8 ld16(const bh16* p) {
  return __builtin_bit_cast(bf16x8, *(const u32x4*)p);
}
DEVI bf16x8 ld16b(const char* p) {
  return __builtin_bit_cast(bf16x8, *(const u32x4*)p);
}
DEVI f32x4 mfma16(bf16x8 a, bf16x8 b, f32x4 c) {
  return __builtin_amdgcn_mfma_f32_16x16x32_bf16(a, b, c, 0, 0, 0);
}
DEVI void async16(const void* g, void* l) {
  __builtin_amdgcn_global_load_lds(
      (const __attribute__((address_space(1))) void*)g,
      (__attribute__((address_space(3))) void*)l, 16, 0, 0);
}

// ---------------------------------------------------------------------------
// All weight transposes (f32 [K][N] -> bf16 [N][K]) in ONE launch.
// ---------------------------------------------------------------------------
DEVI void tcvt_body(const float* in, bh16* out, int K, int N, int n0, int k0) {
  __shared__ float t[32][33];
  int tx = threadIdx.x & 31, ty = threadIdx.x >> 5;  // 32 x 8
#pragma unroll
  for (int i = 0; i < 4; i++)
    t[ty + 8 * i][tx] = in[(size_t)(k0 + ty + 8 * i) * N + n0 + tx];
  __syncthreads();
#pragma unroll
  for (int i = 0; i < 4; i++)
    out[(size_t)(n0 + ty + 8 * i) * K + k0 + tx] = f2bf(t[tx][ty + 8 * i]);
}

__global__ __launch_bounds__(256) void tcvt_all(
    const float* __restrict__ w_in, const float* __restrict__ wq,
    const float* __restrict__ wk, const float* __restrict__ wv,
    const float* __restrict__ wfc, const float* __restrict__ w1,
    const float* __restrict__ w2, bh16* __restrict__ WinT,
    bh16* __restrict__ WqkvT, bh16* __restrict__ WfcT,
    bh16* __restrict__ W1T, bh16* __restrict__ W2T) {
  int p = blockIdx.x;
  const float* in; bh16* out; int K, N, rem;
  if (p < 160) {                 // w_in: 512x320, 16x10 tiles, 1 layer
    in = w_in; out = WinT; K = 320; N = 512; rem = p;
  } else if (p < 160 + 1536) {   // wq -> WqkvT rows [0,512)
    rem = p - 160; int l = rem >> 8; rem &= 255;
    in = wq + (size_t)l * 512 * 512; out = WqkvT + (size_t)l * 1536 * 512;
    K = 512; N = 512;
  } else if (p < 160 + 3072) {   // wk -> rows [512,1024)
    rem = p - 160 - 1536; int l = rem >> 8; rem &= 255;
    in = wk + (size_t)l * 512 * 512;
    out = WqkvT + (size_t)l * 1536 * 512 + (size_t)512 * 512;
    K = 512; N = 512;
  } else if (p < 160 + 4608) {   // wv -> rows [1024,1536)
    rem = p - 160 - 3072; int l = rem >> 8; rem &= 255;
    in = wv + (size_t)l * 512 * 512;
    out = WqkvT + (size_t)l * 1536 * 512 + (size_t)1024 * 512;
    K = 512; N = 512;
  } else if (p < 160 + 6144) {   // wfc
    rem = p - 160 - 4608; int l = rem >> 8; rem &= 255;
    in = wfc + (size_t)l * 512 * 512; out = WfcT + (size_t)l * 512 * 512;
    K = 512; N = 512;
  } else if (p < 160 + 6144 + 6144) {  // w1: [512][2048] -> [2048][512]
    rem = p - 160 - 6144; int l = rem >> 10; rem &= 1023;
    in = w1 + (size_t)l * 512 * 2048; out = W1T + (size_t)l * 2048 * 512;
    K = 512; N = 2048;
  } else {                        // w2: [2048][512] -> [512][2048]
    rem = p - 160 - 12288; int l = rem >> 10; rem &= 1023;
    in = w2 + (size_t)l * 2048 * 512; out = W2T + (size_t)l * 512 * 2048;
    K = 2048; N = 512;
  }
  int nt = N >> 5;
  int n0 = (rem % nt) * 32, k0 = (rem / nt) * 32;
  tcvt_body(in, out, K, N, n0, k0);
}

// bias concat: bq|bk|bv -> [L][1536] f32
__global__ __launch_bounds__(256) void bcat(
    const float* __restrict__ bq, const float* __restrict__ bk,
    const float* __restrict__ bv, float* __restrict__ out) {
  int l = blockIdx.x;
  for (int j = threadIdx.x; j < 1536; j += 256) {
    float v = (j < 512) ? bq[l * 512 + j]
            : (j < 1024) ? bk[l * 512 + j - 512] : bv[l * 512 + j - 1024];
    out[l * 1536 + j] = v;
  }
}

// f32 -> bf16 convert (padded_input)
__global__ __launch_bounds__(256) void cvt_in(
    const float* __restrict__ in, bh16* __restrict__ out, int n4) {
  int i = blockIdx.x * 256 + threadIdx.x;
  if (i < n4) {
    float4 v = ((const float4*)in)[i];
    u32x2 pk;
    pk[0] = (unsigned)f2bf(v.x) | ((unsigned)f2bf(v.y) << 16);
    pk[1] = (unsigned)f2bf(v.z) | ((unsigned)f2bf(v.w) << 16);
    *(u32x2*)(out + (size_t)i * 4) = pk;
  }
}

// ---------------------------------------------------------------------------
// GEMM: C[M][N] = A[M][K](bf16) * Bt[N][K](bf16)^T + bias. R8 2-phase dbuf
// + T2 XOR swizzle + XCD swizzle (generic over panel count). Padding-panel
// skip. QKV=1: n0>=1024 blocks write vt[(b*512+vc)][t] directly.
// SPLITK=2: grid doubled; upper half computes K-half 1 with no bias and
// writes f32 partial at Cout + M*N (ln2_res_k sums the two partials).
// ---------------------------------------------------------------------------
template <int BM, int BN, int RELU, int OUTF32, int QKV, int SPLITK = 1>
__global__ __launch_bounds__(256) void gemm_bt(
    const bh16* __restrict__ A, const bh16* __restrict__ Bt,
    const float* __restrict__ bias, void* __restrict__ Cout,
    bh16* __restrict__ vtOut, const int* __restrict__ lens,
    int M, int N, int K) {
  constexpr int BK = 64;
  constexpr int PX = (8192 / BM) / 8;           // m-slots per XCD (8 or 16)
  constexpr int PXS = (PX == 8) ? 3 : 4;
  __shared__ __align__(16) bh16 As[2][BM * BK];
  __shared__ __align__(16) bh16 Bs[2][BN * BK];
  const int tid = threadIdx.x;
  const int wave = tid >> 6, lane = tid & 63;
  const int lq = lane & 15, grp = lane >> 4;
  int p = blockIdx.x;
  int s2 = 0;
  if (SPLITK == 2) {
    int half = gridDim.x >> 1;
    if (p >= half) { s2 = 1; p -= half; }
  }
  const int xcd = p & 7, idx = p >> 3;
  const int m0 = (((idx & (PX - 1)) << 3) | xcd) * BM;
  const int n0 = (idx >> PXS) * BN;
  // padding-panel skip (rows >= len[b] never escape downstream masking)
  if ((m0 & 1023) >= lens[m0 >> 10]) return;
  constexpr int FM = BM / 32, FN = BN / 32;
  const int wr = wave >> 1, wc = wave & 1;
  f32x4 acc[FM][FN] = {};

  const int nk = K / BK / SPLITK;
  const int kb0 = s2 * nk;
  auto stage = [&](int buf, int ktg) {
#pragma unroll
    for (int i = 0; i < BM / 32; ++i) {
      int off = i * 4096 + wave * 1024 + lane * 16;
      int row = off >> 7, col = off & 127;
      int sw = (row & 7) << 4;
      const char* g =
          (const char*)A + ((size_t)(m0 + row) * K + ktg * BK) * 2 + (col ^ sw);
      async16(g, (char*)As[buf] + off);
    }
#pragma unroll
    for (int i = 0; i < BN / 32; ++i) {
      int off = i * 4096 + wave * 1024 + lane * 16;
      int row = off >> 7, col = off & 127;
      int sw = (row & 7) << 4;
      const char* g =
          (const char*)Bt + ((size_t)(n0 + row) * K + ktg * BK) * 2 + (col ^ sw);
      async16(g, (char*)Bs[buf] + off);
    }
  };

  stage(0, kb0);
  for (int kt = 0; kt < nk; ++kt) {
    int cur = kt & 1;
    __syncthreads();                 // stage(kt) landed; prev readers done
    if (kt + 1 < nk) stage(cur ^ 1, kb0 + kt + 1);
#pragma unroll
    for (int kk = 0; kk < 2; ++kk) {
      bf16x8 af[FM], bfr[FN];
#pragma unroll
      for (int i = 0; i < FM; ++i) {
        int row = wr * (BM / 2) + i * 16 + lq;
        int sw = (row & 7) << 4;
        af[i] = ld16b((char*)As[cur] + row * 128 + ((kk * 64 + grp * 16) ^ sw));
      }
#pragma unroll
      for (int j = 0; j < FN; ++j) {
        int row = wc * (BN / 2) + j * 16 + lq;
        int sw = (row & 7) << 4;
        bfr[j] = ld16b((char*)Bs[cur] + row * 128 + ((kk * 64 + grp * 16) ^ sw));
      }
      __builtin_amdgcn_s_setprio(1);
#pragma unroll
      for (int i = 0; i < FM; ++i)
#pragma unroll
        for (int j = 0; j < FN; ++j)
          acc[i][j] = mfma16(af[i], bfr[j], acc[i][j]);
      __builtin_amdgcn_s_setprio(0);
    }
  }
  // epilogue: D layout col=lane&15, row=(lane>>4)*4+r  [m89-verified]
  if (QKV && n0 >= 1024) {
#pragma unroll
    for (int i = 0; i < FM; ++i) {
#pragma unroll
      for (int j = 0; j < FN; ++j) {
        int col = n0 + wc * (BN / 2) + j * 16 + lq;
        float bv = bias[col];
        int vc = col - 1024;
        int t0 = m0 + wr * (BM / 2) + i * 16 + grp * 4;
        int bb = t0 >> 10, tl = t0 & 1023;
        u32x2 pk;
        pk[0] = (unsigned)f2bf(acc[i][j][0] + bv) |
                ((unsigned)f2bf(acc[i][j][1] + bv) << 16);
        pk[1] = (unsigned)f2bf(acc[i][j][2] + bv) |
                ((unsigned)f2bf(acc[i][j][3] + bv) << 16);
        *(u32x2*)&vtOut[((size_t)(bb * 512 + vc)) * 1024 + tl] = pk;
      }
    }
    return;
  }
  float* fbase = (float*)Cout + (SPLITK == 2 ? (size_t)s2 * M * N : 0);
#pragma unroll
  for (int i = 0; i < FM; ++i) {
#pragma unroll
    for (int j = 0; j < FN; ++j) {
      int col = n0 + wc * (BN / 2) + j * 16 + lq;
      float bv = (SPLITK == 2 && s2) ? 0.f : bias[col];
#pragma unroll
      for (int r = 0; r < 4; ++r) {
        int row = m0 + wr * (BM / 2) + i * 16 + grp * 4 + r;
        float v = acc[i][j][r] + bv;
        if (RELU) v = fmaxf(v, 0.f);
        if (OUTF32) fbase[(size_t)row * N + col] = v;
        else ((bh16*)Cout)[(size_t)row * N + col] = f2bf(v);
      }
    }
  }
}

// ---------------------------------------------------------------------------
// LayerNorm after input projection: xb = bf16(LN(in)*g+b + pe[t])  (bf16 in)
// ---------------------------------------------------------------------------
__global__ __launch_bounds__(256) void ln_pe_k(
    const bh16* __restrict__ in, const float* __restrict__ g,
    const float* __restrict__ bta, const float* __restrict__ pe,
    bh16* __restrict__ xb) {
  int wave = threadIdx.x >> 6, lane = threadIdx.x & 63;
  int row = blockIdx.x * 4 + wave;
  int t = row & 1023;
  int c0 = lane * 8;
  u32x4 raw = *(const u32x4*)(in + (size_t)row * 512 + c0);
  float v[8];
#pragma unroll
  for (int j = 0; j < 4; j++) {
    v[2 * j] = bf2f((bh16)(raw[j] & 0xffffu));
    v[2 * j + 1] = bf2f((bh16)(raw[j] >> 16));
  }
  float s = 0.f, ss = 0.f;
#pragma unroll
  for (int j = 0; j < 8; j++) { s += v[j]; ss += v[j] * v[j]; }
#pragma unroll
  for (int m = 1; m < 64; m <<= 1) { s += __shfl_xor(s, m); ss += __shfl_xor(ss, m); }
  float mu = s * (1.f / 512.f);
  float rstd = rsqrtf(ss * (1.f / 512.f) - mu * mu + 1e-5f);
  float o[8];
  u32x4 pk;
#pragma unroll
  for (int j = 0; j < 8; j++) {
    int c = c0 + j;
    o[j] = (v[j] - mu) * rstd * g[c] + bta[c] + pe[(size_t)t * 512 + c];
  }
#pragma unroll
  for (int j = 0; j < 4; j++)
    pk[j] = (unsigned)f2bf(o[2 * j]) | ((unsigned)f2bf(o[2 * j + 1]) << 16);
  *(u32x4*)(xb + (size_t)row * 512 + c0) = pk;
}

// ---------------------------------------------------------------------------
// LayerNorm with bf16 residual + pad-mask, in-place xb update (bf16 gout).
// ---------------------------------------------------------------------------
__global__ __launch_bounds__(256) void ln_res_k(
    const bh16* __restrict__ gout, const bh16* res,
    const float* __restrict__ g, const float* __restrict__ bta,
    const int* __restrict__ lens, bh16* xb, float* fout) {
  int wave = threadIdx.x >> 6, lane = threadIdx.x & 63;
  int row = blockIdx.x * 4 + wave;
  int b = row >> 10, t = row & 1023;
  float nonpad = (t < lens[b]) ? 1.f : 0.f;
  int c0 = lane * 8;
  u32x4 graw = *(const u32x4*)(gout + (size_t)row * 512 + c0);
  u32x4 rraw = *(const u32x4*)(res + (size_t)row * 512 + c0);
  float v[8];
#pragma unroll
  for (int j = 0; j < 4; j++) {
    v[2 * j] = bf2f((bh16)(graw[j] & 0xffffu)) + bf2f((bh16)(rraw[j] & 0xffffu));
    v[2 * j + 1] = bf2f((bh16)(graw[j] >> 16)) + bf2f((bh16)(rraw[j] >> 16));
  }
  float s = 0.f, ss = 0.f;
#pragma unroll
  for (int j = 0; j < 8; j++) { s += v[j]; ss += v[j] * v[j]; }
#pragma unroll
  for (int m = 1; m < 64; m <<= 1) { s += __shfl_xor(s, m); ss += __shfl_xor(ss, m); }
  float mu = s * (1.f / 512.f);
  float rstd = rsqrtf(ss * (1.f / 512.f) - mu * mu + 1e-5f);
  float o[8];
  u32x4 pk;
#pragma unroll
  for (int j = 0; j < 8; j++) {
    int c = c0 + j;
    o[j] = ((v[j] - mu) * rstd * g[c] + bta[c]) * nonpad;
  }
#pragma unroll
  for (int j = 0; j < 4; j++)
    pk[j] = (unsigned)f2bf(o[2 * j]) | ((unsigned)f2bf(o[2 * j + 1]) << 16);
  *(u32x4*)(xb + (size_t)row * 512 + c0) = pk;
  if (fout) {
    float4* xo = (float4*)(fout + (size_t)row * 512 + c0);
    xo[0] = make_float4(o[0], o[1], o[2], o[3]);
    xo[1] = make_float4(o[4], o[5], o[6], o[7]);
  }
}

// ---------------------------------------------------------------------------
// LayerNorm summing two f32 split-K partials + bf16 residual, in-place xb.
// ---------------------------------------------------------------------------
__global__ __launch_bounds__(256) void ln2_res_k(
    const float* __restrict__ g0, const float* __restrict__ g1,
    const bh16* res, const float* __restrict__ g,
    const float* __restrict__ bta, const int* __restrict__ lens,
    bh16* xb, float* fout) {
  int wave = threadIdx.x >> 6, lane = threadIdx.x & 63;
  int row = blockIdx.x * 4 + wave;
  int b = row >> 10, t = row & 1023;
  float nonpad = (t < lens[b]) ? 1.f : 0.f;
  int c0 = lane * 8;
  const float* p0 = g0 + (size_t)row * 512 + c0;
  const float* p1 = g1 + (size_t)row * 512 + c0;
  float4 a0 = ((const float4*)p0)[0], a1 = ((const float4*)p0)[1];
  float4 b0 = ((const float4*)p1)[0], b1 = ((const float4*)p1)[1];
  u32x4 rraw = *(const u32x4*)(res + (size_t)row * 512 + c0);
  float v[8] = {a0.x + b0.x, a0.y + b0.y, a0.z + b0.z, a0.w + b0.w,
                a1.x + b1.x, a1.y + b1.y, a1.z + b1.z, a1.w + b1.w};
#pragma unroll
  for (int j = 0; j < 4; j++) {
    v[2 * j] += bf2f((bh16)(rraw[j] & 0xffffu));
    v[2 * j + 1] += bf2f((bh16)(rraw[j] >> 16));
  }
  float s = 0.f, ss = 0.f;
#pragma unroll
  for (int j = 0; j < 8; j++) { s += v[j]; ss += v[j] * v[j]; }
#pragma unroll
  for (int m = 1; m < 64; m <<= 1) { s += __shfl_xor(s, m); ss += __shfl_xor(ss, m); }
  float mu = s * (1.f / 512.f);
  float rstd = rsqrtf(ss * (1.f / 512.f) - mu * mu + 1e-5f);
  float o[8];
  u32x4 pk;
#pragma unroll
  for (int j = 0; j < 8; j++) {
    int c = c0 + j;
    o[j] = ((v[j] - mu) * rstd * g[c] + bta[c]) * nonpad;
  }
#pragma unroll
  for (int j = 0; j < 4; j++)
    pk[j] = (unsigned)f2bf(o[2 * j]) | ((unsigned)f2bf(o[2 * j + 1]) << 16);
  *(u32x4*)(xb + (size_t)row * 512 + c0) = pk;
  if (fout) {
    float4* xo = (float4*)(fout + (size_t)row * 512 + c0);
    xo[0] = make_float4(o[0], o[1], o[2], o[3]);
    xo[1] = make_float4(o[4], o[5], o[6], o[7]);
  }
}

// ---------------------------------------------------------------------------
// Fused flash attention, staged 2-phase, 8 waves x 16 q = 128 q-rows/block.
// grid 512 = {8 qt x 64 bh}, XCD-swizzled (same bh -> same XCD). Per 64-key
// iter: sync -> stage(next K[64][64]+Vt[64][64], T2 swizzle) -> compute.
// ---------------------------------------------------------------------------
__global__ __launch_bounds__(512) void attn_k(
    const bh16* __restrict__ qkv, const bh16* __restrict__ vt,
    const int* __restrict__ lens, bh16* __restrict__ o) {
  constexpr int LDP = 72;
  __shared__ __align__(16) char Ks[2][8192];   // [key 0..63][d 0..63] swz
  __shared__ __align__(16) char Vs[2][8192];   // [d 0..63][t 0..63] swz
  __shared__ __align__(16) bh16 P[8][16 * LDP];
  int p = blockIdx.x;
  int xcd = p & 7, s = p >> 3;          // s in 0..63
  int bh = ((s & 7) << 3) | xcd;
  int qt = s >> 3;                      // 0..7
  int b = bh >> 3, h = bh & 7;
  int len = lens[b];
  if (qt * 128 >= len) return;
  int tid = threadIdx.x;
  int wave = tid >> 6, lane = tid & 63;
  int lq = lane & 15, grp = lane >> 4;

  size_t qrow = (size_t)(b * 1024 + qt * 128 + wave * 16 + lq);
  const bh16* Qp = qkv + qrow * 1536 + h * 64;
  bf16x8 qf0 = ld16(Qp + grp * 8);
  bf16x8 qf1 = ld16(Qp + 32 + grp * 8);
  const char* Kbase = (const char*)(qkv + (size_t)(b * 1024) * 1536 + 512 + h * 64);
  const char* Vbase = (const char*)(vt + (size_t)(bh * 64) * 1024);
  bh16* Pw = P[wave];

  f32x4 oacc[4] = {};
  float m = -1e30f, lsum = 0.f;
  int nkb = (len + 63) >> 6;

  auto stage = [&](int buf, int kb) {
    int off = tid * 16;
    int row = off >> 7, cb = off & 127;
    int sw = (row & 7) << 4;
    async16(Kbase + (size_t)(kb * 64 + row) * 3072 + (cb ^ sw), Ks[buf] + off);
    async16(Vbase + (size_t)row * 2048 + kb * 128 + (cb ^ sw), Vs[buf] + off);
  };

  stage(0, 0);
  for (int kb = 0; kb < nkb; ++kb) {
    int cur = kb & 1;
    __syncthreads();
    if (kb + 1 < nkb) stage(cur ^ 1, kb + 1);
    int k64 = kb * 64;
    f32x4 st[4];
    __builtin_amdgcn_s_setprio(1);
#pragma unroll
    for (int sv = 0; sv < 4; ++sv) {
      int row = sv * 16 + lq, sw = (row & 7) << 4;
      const char* kp = Ks[cur] + row * 128;
      f32x4 z = {};
      z = mfma16(ld16b(kp + ((grp * 16) ^ sw)), qf0, z);
      z = mfma16(ld16b(kp + ((64 + grp * 16) ^ sw)), qf1, z);
      st[sv] = z;
    }
    __builtin_amdgcn_s_setprio(0);
    float tmax = -1e30f;
    if (k64 + 64 > len) {
#pragma unroll
      for (int sv = 0; sv < 4; ++sv)
#pragma unroll
        for (int r = 0; r < 4; ++r) {
          int key = k64 + sv * 16 + grp * 4 + r;
          float v = st[sv][r] * 0.125f;
          v = (key < len) ? v : -1e30f;
          st[sv][r] = v;
          tmax = fmaxf(tmax, v);
        }
    } else {
#pragma unroll
      for (int sv = 0; sv < 4; ++sv)
#pragma unroll
        for (int r = 0; r < 4; ++r) {
          float v = st[sv][r] * 0.125f;
          st[sv][r] = v;
          tmax = fmaxf(tmax, v);
        }
    }
    tmax = fmaxf(tmax, __shfl_xor(tmax, 16));
    tmax = fmaxf(tmax, __shfl_xor(tmax, 32));
    float newm = fmaxf(m, tmax);
    if (!__all(newm - m <= 8.f)) {
      float sc = __expf(m - newm);
      m = newm;
      lsum *= sc;
#pragma unroll
      for (int r = 0; r < 4; ++r) {
        float scr = __shfl(sc, grp * 4 + r);
#pragma unroll
        for (int dt = 0; dt < 4; ++dt) oacc[dt][r] *= scr;
      }
    }
    float rs = 0.f;
#pragma unroll
    for (int sv = 0; sv < 4; ++sv) {
      float p0 = __expf(st[sv][0] - m), p1 = __expf(st[sv][1] - m);
      float p2 = __expf(st[sv][2] - m), p3 = __expf(st[sv][3] - m);
      rs += (p0 + p1) + (p2 + p3);
      u32x2 pk;
      pk[0] = (unsigned)f2bf(p0) | ((unsigned)f2bf(p1) << 16);
      pk[1] = (unsigned)f2bf(p2) | ((unsigned)f2bf(p3) << 16);
      *(u32x2*)&Pw[lq * LDP + sv * 16 + grp * 4] = pk;
    }
    rs += __shfl_xor(rs, 16);
    rs += __shfl_xor(rs, 32);
    lsum += rs;
#pragma unroll
    for (int kk = 0; kk < 2; ++kk) {
      bf16x8 pa = ld16(Pw + lq * LDP + kk * 32 + grp * 8);
      __builtin_amdgcn_s_setprio(1);
#pragma unroll
      for (int dt = 0; dt < 4; ++dt) {
        int row = dt * 16 + lq, sw = (row & 7) << 4;
        bf16x8 vfr = ld16b(Vs[cur] + row * 128 + ((kk * 64 + grp * 16) ^ sw));
        oacc[dt] = mfma16(pa, vfr, oacc[dt]);
      }
      __builtin_amdgcn_s_setprio(0);
    }
  }
#pragma unroll
  for (int r = 0; r < 4; ++r) {
    float li = __shfl(lsum, grp * 4 + r);
    float inv = 1.f / li;
    int row = qt * 128 + wave * 16 + grp * 4 + r;
    bh16* orow = o + (size_t)(b * 1024 + row) * 512 + h * 64;
#pragma unroll
    for (int dt = 0; dt < 4; ++dt) orow[dt * 16 + lq] = f2bf(oacc[dt][r] * inv);
  }
}

// ---------------------------------------------------------------------------
// host
// ---------------------------------------------------------------------------
extern "C" void kernel_launch(void* const* d_in, const int* in_sizes, int n_in,
                              void* d_out, int out_size, void* d_ws, size_t ws_size,
                              hipStream_t stream) {
  const float* padded = (const float*)d_in[0];
  const int* lens = (const int*)d_in[1];
  const float* w_in = (const float*)d_in[2];
  const float* b_in = (const float*)d_in[3];
  const float* ln_in_g = (const float*)d_in[4];
  const float* ln_in_b = (const float*)d_in[5];
  const float* pe = (const float*)d_in[6];
  const float* wq = (const float*)d_in[7];
  const float* bq = (const float*)d_in[8];
  const float* wk = (const float*)d_in[9];
  const float* bk = (const float*)d_in[10];
  const float* wv = (const float*)d_in[11];
  const float* bv = (const float*)d_in[12];
  const float* wfc = (const float*)d_in[13];
  const float* bfc = (const float*)d_in[14];
  const float* ln1_g = (const float*)d_in[15];
  const float* ln1_b = (const float*)d_in[16];
  const float* w1 = (const float*)d_in[17];
  const float* b1 = (const float*)d_in[18];
  const float* w2 = (const float*)d_in[19];
  const float* b2 = (const float*)d_in[20];
  const float* ln2_g = (const float*)d_in[21];
  const float* ln2_b = (const float*)d_in[22];

  char* ws = (char*)d_ws;
  size_t off = 0;
  auto alloc = [&](size_t bytes) -> char* {
    char* p = ws + off;
    off += (bytes + 255) & ~(size_t)255;
    return p;
  };
  bh16* WinT  = (bh16*)alloc((size_t)512 * 320 * 2);
  bh16* WqkvT = (bh16*)alloc((size_t)6 * 1536 * 512 * 2);
  bh16* WfcT  = (bh16*)alloc((size_t)6 * 512 * 512 * 2);
  bh16* W1T   = (bh16*)alloc((size_t)6 * 2048 * 512 * 2);
  bh16* W2T   = (bh16*)alloc((size_t)6 * 512 * 2048 * 2);
  float* bqkv = (float*)alloc((size_t)6 * 1536 * 4);
  bh16* xb    = (bh16*)alloc((size_t)8192 * 512 * 2);
  bh16* qkvb  = (bh16*)alloc((size_t)8192 * 1536 * 2);
  bh16* vt    = (bh16*)alloc((size_t)64 * 64 * 1024 * 2);
  bh16* ob    = (bh16*)alloc((size_t)8192 * 512 * 2);
  float* tmp32 = (float*)alloc((size_t)2 * 8192 * 512 * 4);  // split-K partials
  bh16* tmp16 = (bh16*)alloc((size_t)8192 * 512 * 2);
  bh16* hbuf  = (bh16*)alloc((size_t)8192 * 2048 * 2);
  bh16* padb  = hbuf;  // alias: hbuf is free until w1 GEMM
  if (off > ws_size) return;  // loud failure (output stays poisoned)

  // weights -> bf16 transposed (one launch)
  tcvt_all<<<18592, 256, 0, stream>>>(w_in, wq, wk, wv, wfc, w1, w2,
                                      WinT, WqkvT, WfcT, W1T, W2T);
  bcat<<<6, 256, 0, stream>>>(bq, bk, bv, bqkv);
  cvt_in<<<2560, 256, 0, stream>>>(padded, padb, 655360);

  // input projection (bf16 out) + LN + PE
  gemm_bt<64, 64, 0, 0, 0><<<1024, 256, 0, stream>>>(
      padb, WinT, b_in, tmp16, nullptr, lens, 8192, 512, 320);
  ln_pe_k<<<2048, 256, 0, stream>>>(tmp16, ln_in_g, ln_in_b, pe, xb);

  for (int l = 0; l < 6; ++l) {
    gemm_bt<64, 128, 0, 0, 1><<<1536, 256, 0, stream>>>(
        xb, WqkvT + (size_t)l * 1536 * 512, bqkv + l * 1536, qkvb, vt, lens,
        8192, 1536, 512);
    attn_k<<<512, 512, 0, stream>>>(qkvb, vt, lens, ob);
    gemm_bt<64, 64, 0, 0, 0><<<1024, 256, 0, stream>>>(
        ob, WfcT + (size_t)l * 512 * 512, bfc + l * 512, tmp16, nullptr, lens,
        8192, 512, 512);
    ln_res_k<<<2048, 256, 0, stream>>>(tmp16, xb, ln1_g + l * 512, ln1_b + l * 512,
                                       lens, xb, nullptr);
    gemm_bt<64, 128, 1, 0, 0><<<2048, 256, 0, stream>>>(
        xb, W1T + (size_t)l * 2048 * 512, b1 + l * 2048, hbuf, nullptr, lens,
        8192, 2048, 512);
    gemm_bt<64, 64, 0, 1, 0, 2><<<2048, 256, 0, stream>>>(
        hbuf, W2T + (size_t)l * 512 * 2048, b2 + l * 512, tmp32, nullptr, lens,
        8192, 512, 2048);
    ln2_res_k<<<2048, 256, 0, stream>>>(tmp32, tmp32 + (size_t)8192 * 512, xb,
                                        ln2_g + l * 512, ln2_b + l * 512,
                                        lens, xb, (l == 5) ? (float*)d_out : nullptr);
  }
}

// Round 13
// 792.644 us; speedup vs baseline: 1.0336x; 1.0336x over previous
//
#include <hip/hip_runtime.h>
#include <hip/hip_bf16.h>

// ---------------------------------------------------------------------------
// Transformer encoder, B=8 T=1024 D_IN=320 L=6 H=8 DK=DV=64 DM=512 DI=2048.
// R12 post-mortem: w2 split-K f32 partials = +48MB/layer traffic (net loss);
//   qkv BM64xBN128 halved MFMA/staging intensity. Reverted both to R11.
// R13 = R11 config + (input proj bf16 out, ln_pe bf16 in) + single-launch
//   preamble (tcvt_all includes bcat + cvt_in segments).
// ---------------------------------------------------------------------------

typedef unsigned short bh16;                                  // bf16 bits
typedef __bf16 bf16x8 __attribute__((ext_vector_type(8)));
typedef float f32x4 __attribute__((ext_vector_type(4)));
typedef unsigned int u32x4 __attribute__((ext_vector_type(4)));
typedef unsigned int u32x2 __attribute__((ext_vector_type(2)));

#define DEVI static __device__ __forceinline__

DEVI bh16 f2bf(float f) {
  union { float f; unsigned u; } x; x.f = f;
  unsigned r = x.u + 0x7fffu + ((x.u >> 16) & 1u);
  return (bh16)(r >> 16);
}
DEVI float bf2f(bh16 u) {
  union { unsigned u; float f; } x; x.u = ((unsigned)u) << 16; return x.f;
}
DEVI bf16x8 ld16(const bh16* p) {
  return __builtin_bit_cast(bf16x8, *(const u32x4*)p);
}
DEVI bf16x8 ld16b(const char* p) {
  return __builtin_bit_cast(bf16x8, *(const u32x4*)p);
}
DEVI f32x4 mfma16(bf16x8 a, bf16x8 b, f32x4 c) {
  return __builtin_amdgcn_mfma_f32_16x16x32_bf16(a, b, c, 0, 0, 0);
}
DEVI void async16(const void* g, void* l) {
  __builtin_amdgcn_global_load_lds(
      (const __attribute__((address_space(1))) void*)g,
      (__attribute__((address_space(3))) void*)l, 16, 0, 0);
}

// ---------------------------------------------------------------------------
// Whole preamble in ONE launch: weight transposes (f32 [K][N] -> bf16 [N][K]),
// bias concat, input f32->bf16 convert. Segments decoded from blockIdx.x.
// ---------------------------------------------------------------------------
DEVI void tcvt_body(const float* in, bh16* out, int K, int N, int n0, int k0) {
  __shared__ float t[32][33];
  int tx = threadIdx.x & 31, ty = threadIdx.x >> 5;  // 32 x 8
#pragma unroll
  for (int i = 0; i < 4; i++)
    t[ty + 8 * i][tx] = in[(size_t)(k0 + ty + 8 * i) * N + n0 + tx];
  __syncthreads();
#pragma unroll
  for (int i = 0; i < 4; i++)
    out[(size_t)(n0 + ty + 8 * i) * K + k0 + tx] = f2bf(t[tx][ty + 8 * i]);
}

__global__ __launch_bounds__(256) void tcvt_all(
    const float* __restrict__ w_in, const float* __restrict__ wq,
    const float* __restrict__ wk, const float* __restrict__ wv,
    const float* __restrict__ wfc, const float* __restrict__ w1,
    const float* __restrict__ w2, bh16* __restrict__ WinT,
    bh16* __restrict__ WqkvT, bh16* __restrict__ WfcT,
    bh16* __restrict__ W1T, bh16* __restrict__ W2T,
    const float* __restrict__ bq, const float* __restrict__ bk,
    const float* __restrict__ bv, float* __restrict__ bqkv,
    const float* __restrict__ padded, bh16* __restrict__ padb) {
  int p = blockIdx.x;
  if (p >= 18592) {
    if (p < 18598) {               // bcat: 6 blocks
      int l = p - 18592;
      for (int j = threadIdx.x; j < 1536; j += 256) {
        float v = (j < 512) ? bq[l * 512 + j]
                : (j < 1024) ? bk[l * 512 + j - 512] : bv[l * 512 + j - 1024];
        bqkv[l * 1536 + j] = v;
      }
    } else {                        // cvt_in: 2560 blocks, 655360 float4s
      int i = (p - 18598) * 256 + threadIdx.x;
      if (i < 655360) {
        float4 v = ((const float4*)padded)[i];
        u32x2 pk;
        pk[0] = (unsigned)f2bf(v.x) | ((unsigned)f2bf(v.y) << 16);
        pk[1] = (unsigned)f2bf(v.z) | ((unsigned)f2bf(v.w) << 16);
        *(u32x2*)(padb + (size_t)i * 4) = pk;
      }
    }
    return;
  }
  const float* in; bh16* out; int K, N, rem;
  if (p < 160) {                 // w_in: 512x320, 16x10 tiles, 1 layer
    in = w_in; out = WinT; K = 320; N = 512; rem = p;
  } else if (p < 160 + 1536) {   // wq -> WqkvT rows [0,512)
    rem = p - 160; int l = rem >> 8; rem &= 255;
    in = wq + (size_t)l * 512 * 512; out = WqkvT + (size_t)l * 1536 * 512;
    K = 512; N = 512;
  } else if (p < 160 + 3072) {   // wk -> rows [512,1024)
    rem = p - 160 - 1536; int l = rem >> 8; rem &= 255;
    in = wk + (size_t)l * 512 * 512;
    out = WqkvT + (size_t)l * 1536 * 512 + (size_t)512 * 512;
    K = 512; N = 512;
  } else if (p < 160 + 4608) {   // wv -> rows [1024,1536)
    rem = p - 160 - 3072; int l = rem >> 8; rem &= 255;
    in = wv + (size_t)l * 512 * 512;
    out = WqkvT + (size_t)l * 1536 * 512 + (size_t)1024 * 512;
    K = 512; N = 512;
  } else if (p < 160 + 6144) {   // wfc
    rem = p - 160 - 4608; int l = rem >> 8; rem &= 255;
    in = wfc + (size_t)l * 512 * 512; out = WfcT + (size_t)l * 512 * 512;
    K = 512; N = 512;
  } else if (p < 160 + 6144 + 6144) {  // w1: [512][2048] -> [2048][512]
    rem = p - 160 - 6144; int l = rem >> 10; rem &= 1023;
    in = w1 + (size_t)l * 512 * 2048; out = W1T + (size_t)l * 2048 * 512;
    K = 512; N = 2048;
  } else {                        // w2: [2048][512] -> [512][2048]
    rem = p - 160 - 12288; int l = rem >> 10; rem &= 1023;
    in = w2 + (size_t)l * 2048 * 512; out = W2T + (size_t)l * 512 * 2048;
    K = 2048; N = 512;
  }
  int nt = N >> 5;
  int n0 = (rem % nt) * 32, k0 = (rem / nt) * 32;
  tcvt_body(in, out, K, N, n0, k0);
}

// ---------------------------------------------------------------------------
// GEMM: C[M][N] = A[M][K](bf16) * Bt[N][K](bf16)^T + bias. R8 2-phase dbuf
// + T2 XOR swizzle + XCD swizzle (generic over panel count). Padding-panel
// skip. QKV=1: n0>=1024 blocks write vt[(b*512+vc)][t] directly.
// ---------------------------------------------------------------------------
template <int BM, int BN, int RELU, int OUTF32, int QKV>
__global__ __launch_bounds__(256) void gemm_bt(
    const bh16* __restrict__ A, const bh16* __restrict__ Bt,
    const float* __restrict__ bias, void* __restrict__ Cout,
    bh16* __restrict__ vtOut, const int* __restrict__ lens,
    int M, int N, int K) {
  constexpr int BK = 64;
  constexpr int PX = (8192 / BM) / 8;           // m-slots per XCD (8 or 16)
  constexpr int PXS = (PX == 8) ? 3 : 4;
  __shared__ __align__(16) bh16 As[2][BM * BK];
  __shared__ __align__(16) bh16 Bs[2][BN * BK];
  const int tid = threadIdx.x;
  const int wave = tid >> 6, lane = tid & 63;
  const int lq = lane & 15, grp = lane >> 4;
  const int p = blockIdx.x;
  const int xcd = p & 7, idx = p >> 3;
  const int m0 = (((idx & (PX - 1)) << 3) | xcd) * BM;
  const int n0 = (idx >> PXS) * BN;
  // padding-panel skip (rows >= len[b] never escape downstream masking)
  if ((m0 & 1023) >= lens[m0 >> 10]) return;
  constexpr int FM = BM / 32, FN = BN / 32;
  const int wr = wave >> 1, wc = wave & 1;
  f32x4 acc[FM][FN] = {};

  const int nk = K / BK;
  auto stage = [&](int buf, int kt) {
#pragma unroll
    for (int i = 0; i < BM / 32; ++i) {
      int off = i * 4096 + wave * 1024 + lane * 16;
      int row = off >> 7, col = off & 127;
      int sw = (row & 7) << 4;
      const char* g =
          (const char*)A + ((size_t)(m0 + row) * K + kt * BK) * 2 + (col ^ sw);
      async16(g, (char*)As[buf] + off);
    }
#pragma unroll
    for (int i = 0; i < BN / 32; ++i) {
      int off = i * 4096 + wave * 1024 + lane * 16;
      int row = off >> 7, col = off & 127;
      int sw = (row & 7) << 4;
      const char* g =
          (const char*)Bt + ((size_t)(n0 + row) * K + kt * BK) * 2 + (col ^ sw);
      async16(g, (char*)Bs[buf] + off);
    }
  };

  stage(0, 0);
  for (int kt = 0; kt < nk; ++kt) {
    int cur = kt & 1;
    __syncthreads();                 // stage(kt) landed; prev readers done
    if (kt + 1 < nk) stage(cur ^ 1, kt + 1);
#pragma unroll
    for (int kk = 0; kk < 2; ++kk) {
      bf16x8 af[FM], bfr[FN];
#pragma unroll
      for (int i = 0; i < FM; ++i) {
        int row = wr * (BM / 2) + i * 16 + lq;
        int sw = (row & 7) << 4;
        af[i] = ld16b((char*)As[cur] + row * 128 + ((kk * 64 + grp * 16) ^ sw));
      }
#pragma unroll
      for (int j = 0; j < FN; ++j) {
        int row = wc * (BN / 2) + j * 16 + lq;
        int sw = (row & 7) << 4;
        bfr[j] = ld16b((char*)Bs[cur] + row * 128 + ((kk * 64 + grp * 16) ^ sw));
      }
      __builtin_amdgcn_s_setprio(1);
#pragma unroll
      for (int i = 0; i < FM; ++i)
#pragma unroll
        for (int j = 0; j < FN; ++j)
          acc[i][j] = mfma16(af[i], bfr[j], acc[i][j]);
      __builtin_amdgcn_s_setprio(0);
    }
  }
  // epilogue: D layout col=lane&15, row=(lane>>4)*4+r  [m89-verified]
  if (QKV && n0 >= 1024) {
#pragma unroll
    for (int i = 0; i < FM; ++i) {
#pragma unroll
      for (int j = 0; j < FN; ++j) {
        int col = n0 + wc * (BN / 2) + j * 16 + lq;
        float bv = bias[col];
        int vc = col - 1024;
        int t0 = m0 + wr * (BM / 2) + i * 16 + grp * 4;
        int bb = t0 >> 10, tl = t0 & 1023;
        u32x2 pk;
        pk[0] = (unsigned)f2bf(acc[i][j][0] + bv) |
                ((unsigned)f2bf(acc[i][j][1] + bv) << 16);
        pk[1] = (unsigned)f2bf(acc[i][j][2] + bv) |
                ((unsigned)f2bf(acc[i][j][3] + bv) << 16);
        *(u32x2*)&vtOut[((size_t)(bb * 512 + vc)) * 1024 + tl] = pk;
      }
    }
    return;
  }
#pragma unroll
  for (int i = 0; i < FM; ++i) {
#pragma unroll
    for (int j = 0; j < FN; ++j) {
      int col = n0 + wc * (BN / 2) + j * 16 + lq;
      float bv = bias[col];
#pragma unroll
      for (int r = 0; r < 4; ++r) {
        int row = m0 + wr * (BM / 2) + i * 16 + grp * 4 + r;
        float v = acc[i][j][r] + bv;
        if (RELU) v = fmaxf(v, 0.f);
        if (OUTF32) ((float*)Cout)[(size_t)row * N + col] = v;
        else ((bh16*)Cout)[(size_t)row * N + col] = f2bf(v);
      }
    }
  }
}

// ---------------------------------------------------------------------------
// LayerNorm after input projection: xb = bf16(LN(in)*g+b + pe[t])  (bf16 in)
// ---------------------------------------------------------------------------
__global__ __launch_bounds__(256) void ln_pe_k(
    const bh16* __restrict__ in, const float* __restrict__ g,
    const float* __restrict__ bta, const float* __restrict__ pe,
    bh16* __restrict__ xb) {
  int wave = threadIdx.x >> 6, lane = threadIdx.x & 63;
  int row = blockIdx.x * 4 + wave;
  int t = row & 1023;
  int c0 = lane * 8;
  u32x4 raw = *(const u32x4*)(in + (size_t)row * 512 + c0);
  float v[8];
#pragma unroll
  for (int j = 0; j < 4; j++) {
    v[2 * j] = bf2f((bh16)(raw[j] & 0xffffu));
    v[2 * j + 1] = bf2f((bh16)(raw[j] >> 16));
  }
  float s = 0.f, ss = 0.f;
#pragma unroll
  for (int j = 0; j < 8; j++) { s += v[j]; ss += v[j] * v[j]; }
#pragma unroll
  for (int m = 1; m < 64; m <<= 1) { s += __shfl_xor(s, m); ss += __shfl_xor(ss, m); }
  float mu = s * (1.f / 512.f);
  float rstd = rsqrtf(ss * (1.f / 512.f) - mu * mu + 1e-5f);
  float o[8];
  u32x4 pk;
#pragma unroll
  for (int j = 0; j < 8; j++) {
    int c = c0 + j;
    o[j] = (v[j] - mu) * rstd * g[c] + bta[c] + pe[(size_t)t * 512 + c];
  }
#pragma unroll
  for (int j = 0; j < 4; j++)
    pk[j] = (unsigned)f2bf(o[2 * j]) | ((unsigned)f2bf(o[2 * j + 1]) << 16);
  *(u32x4*)(xb + (size_t)row * 512 + c0) = pk;
}

// ---------------------------------------------------------------------------
// LayerNorm with bf16 residual + pad-mask, in-place xb update (bf16 gout).
// ---------------------------------------------------------------------------
__global__ __launch_bounds__(256) void ln_res_k(
    const bh16* __restrict__ gout, const bh16* res,
    const float* __restrict__ g, const float* __restrict__ bta,
    const int* __restrict__ lens, bh16* xb, float* fout) {
  int wave = threadIdx.x >> 6, lane = threadIdx.x & 63;
  int row = blockIdx.x * 4 + wave;
  int b = row >> 10, t = row & 1023;
  float nonpad = (t < lens[b]) ? 1.f : 0.f;
  int c0 = lane * 8;
  u32x4 graw = *(const u32x4*)(gout + (size_t)row * 512 + c0);
  u32x4 rraw = *(const u32x4*)(res + (size_t)row * 512 + c0);
  float v[8];
#pragma unroll
  for (int j = 0; j < 4; j++) {
    v[2 * j] = bf2f((bh16)(graw[j] & 0xffffu)) + bf2f((bh16)(rraw[j] & 0xffffu));
    v[2 * j + 1] = bf2f((bh16)(graw[j] >> 16)) + bf2f((bh16)(rraw[j] >> 16));
  }
  float s = 0.f, ss = 0.f;
#pragma unroll
  for (int j = 0; j < 8; j++) { s += v[j]; ss += v[j] * v[j]; }
#pragma unroll
  for (int m = 1; m < 64; m <<= 1) { s += __shfl_xor(s, m); ss += __shfl_xor(ss, m); }
  float mu = s * (1.f / 512.f);
  float rstd = rsqrtf(ss * (1.f / 512.f) - mu * mu + 1e-5f);
  float o[8];
  u32x4 pk;
#pragma unroll
  for (int j = 0; j < 8; j++) {
    int c = c0 + j;
    o[j] = ((v[j] - mu) * rstd * g[c] + bta[c]) * nonpad;
  }
#pragma unroll
  for (int j = 0; j < 4; j++)
    pk[j] = (unsigned)f2bf(o[2 * j]) | ((unsigned)f2bf(o[2 * j + 1]) << 16);
  *(u32x4*)(xb + (size_t)row * 512 + c0) = pk;
  if (fout) {
    float4* xo = (float4*)(fout + (size_t)row * 512 + c0);
    xo[0] = make_float4(o[0], o[1], o[2], o[3]);
    xo[1] = make_float4(o[4], o[5], o[6], o[7]);
  }
}

// ---------------------------------------------------------------------------
// Fused flash attention, staged 2-phase, 8 waves x 16 q = 128 q-rows/block.
// grid 512 = {8 qt x 64 bh}, XCD-swizzled (same bh -> same XCD). Per 64-key
// iter: sync -> stage(next K[64][64]+Vt[64][64], T2 swizzle) -> compute.
// ---------------------------------------------------------------------------
__global__ __launch_bounds__(512) void attn_k(
    const bh16* __restrict__ qkv, const bh16* __restrict__ vt,
    const int* __restrict__ lens, bh16* __restrict__ o) {
  constexpr int LDP = 72;
  __shared__ __align__(16) char Ks[2][8192];   // [key 0..63][d 0..63] swz
  __shared__ __align__(16) char Vs[2][8192];   // [d 0..63][t 0..63] swz
  __shared__ __align__(16) bh16 P[8][16 * LDP];
  int p = blockIdx.x;
  int xcd = p & 7, s = p >> 3;          // s in 0..63
  int bh = ((s & 7) << 3) | xcd;
  int qt = s >> 3;                      // 0..7
  int b = bh >> 3, h = bh & 7;
  int len = lens[b];
  if (qt * 128 >= len) return;
  int tid = threadIdx.x;
  int wave = tid >> 6, lane = tid & 63;
  int lq = lane & 15, grp = lane >> 4;

  size_t qrow = (size_t)(b * 1024 + qt * 128 + wave * 16 + lq);
  const bh16* Qp = qkv + qrow * 1536 + h * 64;
  bf16x8 qf0 = ld16(Qp + grp * 8);
  bf16x8 qf1 = ld16(Qp + 32 + grp * 8);
  const char* Kbase = (const char*)(qkv + (size_t)(b * 1024) * 1536 + 512 + h * 64);
  const char* Vbase = (const char*)(vt + (size_t)(bh * 64) * 1024);
  bh16* Pw = P[wave];

  f32x4 oacc[4] = {};
  float m = -1e30f, lsum = 0.f;
  int nkb = (len + 63) >> 6;

  auto stage = [&](int buf, int kb) {
    int off = tid * 16;
    int row = off >> 7, cb = off & 127;
    int sw = (row & 7) << 4;
    async16(Kbase + (size_t)(kb * 64 + row) * 3072 + (cb ^ sw), Ks[buf] + off);
    async16(Vbase + (size_t)row * 2048 + kb * 128 + (cb ^ sw), Vs[buf] + off);
  };

  stage(0, 0);
  for (int kb = 0; kb < nkb; ++kb) {
    int cur = kb & 1;
    __syncthreads();
    if (kb + 1 < nkb) stage(cur ^ 1, kb + 1);
    int k64 = kb * 64;
    f32x4 st[4];
    __builtin_amdgcn_s_setprio(1);
#pragma unroll
    for (int sv = 0; sv < 4; ++sv) {
      int row = sv * 16 + lq, sw = (row & 7) << 4;
      const char* kp = Ks[cur] + row * 128;
      f32x4 z = {};
      z = mfma16(ld16b(kp + ((grp * 16) ^ sw)), qf0, z);
      z = mfma16(ld16b(kp + ((64 + grp * 16) ^ sw)), qf1, z);
      st[sv] = z;
    }
    __builtin_amdgcn_s_setprio(0);
    float tmax = -1e30f;
    if (k64 + 64 > len) {
#pragma unroll
      for (int sv = 0; sv < 4; ++sv)
#pragma unroll
        for (int r = 0; r < 4; ++r) {
          int key = k64 + sv * 16 + grp * 4 + r;
          float v = st[sv][r] * 0.125f;
          v = (key < len) ? v : -1e30f;
          st[sv][r] = v;
          tmax = fmaxf(tmax, v);
        }
    } else {
#pragma unroll
      for (int sv = 0; sv < 4; ++sv)
#pragma unroll
        for (int r = 0; r < 4; ++r) {
          float v = st[sv][r] * 0.125f;
          st[sv][r] = v;
          tmax = fmaxf(tmax, v);
        }
    }
    tmax = fmaxf(tmax, __shfl_xor(tmax, 16));
    tmax = fmaxf(tmax, __shfl_xor(tmax, 32));
    float newm = fmaxf(m, tmax);
    if (!__all(newm - m <= 8.f)) {
      float sc = __expf(m - newm);
      m = newm;
      lsum *= sc;
#pragma unroll
      for (int r = 0; r < 4; ++r) {
        float scr = __shfl(sc, grp * 4 + r);
#pragma unroll
        for (int dt = 0; dt < 4; ++dt) oacc[dt][r] *= scr;
      }
    }
    float rs = 0.f;
#pragma unroll
    for (int sv = 0; sv < 4; ++sv) {
      float p0 = __expf(st[sv][0] - m), p1 = __expf(st[sv][1] - m);
      float p2 = __expf(st[sv][2] - m), p3 = __expf(st[sv][3] - m);
      rs += (p0 + p1) + (p2 + p3);
      u32x2 pk;
      pk[0] = (unsigned)f2bf(p0) | ((unsigned)f2bf(p1) << 16);
      pk[1] = (unsigned)f2bf(p2) | ((unsigned)f2bf(p3) << 16);
      *(u32x2*)&Pw[lq * LDP + sv * 16 + grp * 4] = pk;
    }
    rs += __shfl_xor(rs, 16);
    rs += __shfl_xor(rs, 32);
    lsum += rs;
#pragma unroll
    for (int kk = 0; kk < 2; ++kk) {
      bf16x8 pa = ld16(Pw + lq * LDP + kk * 32 + grp * 8);
      __builtin_amdgcn_s_setprio(1);
#pragma unroll
      for (int dt = 0; dt < 4; ++dt) {
        int row = dt * 16 + lq, sw = (row & 7) << 4;
        bf16x8 vfr = ld16b(Vs[cur] + row * 128 + ((kk * 64 + grp * 16) ^ sw));
        oacc[dt] = mfma16(pa, vfr, oacc[dt]);
      }
      __builtin_amdgcn_s_setprio(0);
    }
  }
#pragma unroll
  for (int r = 0; r < 4; ++r) {
    float li = __shfl(lsum, grp * 4 + r);
    float inv = 1.f / li;
    int row = qt * 128 + wave * 16 + grp * 4 + r;
    bh16* orow = o + (size_t)(b * 1024 + row) * 512 + h * 64;
#pragma unroll
    for (int dt = 0; dt < 4; ++dt) orow[dt * 16 + lq] = f2bf(oacc[dt][r] * inv);
  }
}

// ---------------------------------------------------------------------------
// host
// ---------------------------------------------------------------------------
extern "C" void kernel_launch(void* const* d_in, const int* in_sizes, int n_in,
                              void* d_out, int out_size, void* d_ws, size_t ws_size,
                              hipStream_t stream) {
  const float* padded = (const float*)d_in[0];
  const int* lens = (const int*)d_in[1];
  const float* w_in = (const float*)d_in[2];
  const float* b_in = (const float*)d_in[3];
  const float* ln_in_g = (const float*)d_in[4];
  const float* ln_in_b = (const float*)d_in[5];
  const float* pe = (const float*)d_in[6];
  const float* wq = (const float*)d_in[7];
  const float* bq = (const float*)d_in[8];
  const float* wk = (const float*)d_in[9];
  const float* bk = (const float*)d_in[10];
  const float* wv = (const float*)d_in[11];
  const float* bv = (const float*)d_in[12];
  const float* wfc = (const float*)d_in[13];
  const float* bfc = (const float*)d_in[14];
  const float* ln1_g = (const float*)d_in[15];
  const float* ln1_b = (const float*)d_in[16];
  const float* w1 = (const float*)d_in[17];
  const float* b1 = (const float*)d_in[18];
  const float* w2 = (const float*)d_in[19];
  const float* b2 = (const float*)d_in[20];
  const float* ln2_g = (const float*)d_in[21];
  const float* ln2_b = (const float*)d_in[22];

  char* ws = (char*)d_ws;
  size_t off = 0;
  auto alloc = [&](size_t bytes) -> char* {
    char* p = ws + off;
    off += (bytes + 255) & ~(size_t)255;
    return p;
  };
  bh16* WinT  = (bh16*)alloc((size_t)512 * 320 * 2);
  bh16* WqkvT = (bh16*)alloc((size_t)6 * 1536 * 512 * 2);
  bh16* WfcT  = (bh16*)alloc((size_t)6 * 512 * 512 * 2);
  bh16* W1T   = (bh16*)alloc((size_t)6 * 2048 * 512 * 2);
  bh16* W2T   = (bh16*)alloc((size_t)6 * 512 * 2048 * 2);
  float* bqkv = (float*)alloc((size_t)6 * 1536 * 4);
  bh16* xb    = (bh16*)alloc((size_t)8192 * 512 * 2);
  bh16* qkvb  = (bh16*)alloc((size_t)8192 * 1536 * 2);
  bh16* vt    = (bh16*)alloc((size_t)64 * 64 * 1024 * 2);
  bh16* ob    = (bh16*)alloc((size_t)8192 * 512 * 2);
  bh16* tmp16 = (bh16*)alloc((size_t)8192 * 512 * 2);
  bh16* hbuf  = (bh16*)alloc((size_t)8192 * 2048 * 2);
  bh16* padb  = hbuf;  // alias: hbuf is free until w1 GEMM
  if (off > ws_size) return;  // loud failure (output stays poisoned)

  // preamble: all weight transposes + bias concat + input convert, 1 launch
  tcvt_all<<<21158, 256, 0, stream>>>(w_in, wq, wk, wv, wfc, w1, w2,
                                      WinT, WqkvT, WfcT, W1T, W2T,
                                      bq, bk, bv, bqkv, padded, padb);

  // input projection (bf16 out) + LN + PE
  gemm_bt<64, 64, 0, 0, 0><<<1024, 256, 0, stream>>>(
      padb, WinT, b_in, tmp16, nullptr, lens, 8192, 512, 320);
  ln_pe_k<<<2048, 256, 0, stream>>>(tmp16, ln_in_g, ln_in_b, pe, xb);

  for (int l = 0; l < 6; ++l) {
    gemm_bt<128, 128, 0, 0, 1><<<768, 256, 0, stream>>>(
        xb, WqkvT + (size_t)l * 1536 * 512, bqkv + l * 1536, qkvb, vt, lens,
        8192, 1536, 512);
    attn_k<<<512, 512, 0, stream>>>(qkvb, vt, lens, ob);
    gemm_bt<64, 64, 0, 0, 0><<<1024, 256, 0, stream>>>(
        ob, WfcT + (size_t)l * 512 * 512, bfc + l * 512, tmp16, nullptr, lens,
        8192, 512, 512);
    ln_res_k<<<2048, 256, 0, stream>>>(tmp16, xb, ln1_g + l * 512, ln1_b + l * 512,
                                       lens, xb, nullptr);
    gemm_bt<64, 128, 1, 0, 0><<<2048, 256, 0, stream>>>(
        xb, W1T + (size_t)l * 2048 * 512, b1 + l * 2048, hbuf, nullptr, lens,
        8192, 2048, 512);
    gemm_bt<64, 64, 0, 0, 0><<<1024, 256, 0, stream>>>(
        hbuf, W2T + (size_t)l * 512 * 2048, b2 + l * 512, tmp16, nullptr, lens,
        8192, 512, 2048);
    ln_res_k<<<2048, 256, 0, stream>>>(tmp16, xb, ln2_g + l * 512, ln2_b + l * 512,
                                       lens, xb, (l == 5) ? (float*)d_out : nullptr);
  }
}